// Round 4
// baseline (32232.135 us; speedup 1.0000x reference)
//
#include <hip/hip_runtime.h>
#include <math.h>

// FNO3D encoder: B=4, CIN=1, 64^3, W=32 ch, L=6 layers, M=32 modes.
// h lives in d_out (fp32 [4][32][64][64][64]); spectral accumulator s in d_ws.

#define BB 4
#define CC 32
#define NN 64
#define MM 32
#define NSITE 4          // perpendicular sites per block (67KB LDS -> 2 blocks/CU)
#define STH 512          // spectral block threads

// ---------------- lift: [x,gx,gy,gz] -> 16 (gelu) -> 32 ----------------
__global__ __launch_bounds__(256) void lift_kernel(
    const float* __restrict__ x,
    const float* __restrict__ lw1, const float* __restrict__ lb1,
    const float* __restrict__ lw2, const float* __restrict__ lb2,
    float* __restrict__ h)
{
    __shared__ float w1[64], b1s[16], w2[512], b2s[32];
    int tid = threadIdx.x;
    if (tid < 64) w1[tid] = lw1[tid];
    if (tid < 16) b1s[tid] = lb1[tid];
    for (int i = tid; i < 512; i += 256) w2[i] = lw2[i];
    if (tid < 32) b2s[tid] = lb2[tid];
    __syncthreads();

    int v = blockIdx.x * 256 + tid;          // 0 .. 1M-1
    int b = v >> 18;
    int vox = v & 262143;
    float feat0 = x[b * 262144 + vox];
    float feat1 = (float)(vox >> 12)        * (1.0f / 63.0f);
    float feat2 = (float)((vox >> 6) & 63)  * (1.0f / 63.0f);
    float feat3 = (float)(vox & 63)         * (1.0f / 63.0f);

    float t1[16];
#pragma unroll
    for (int o = 0; o < 16; ++o) {
        float a = b1s[o];
        a = fmaf(w1[o * 4 + 0], feat0, a);
        a = fmaf(w1[o * 4 + 1], feat1, a);
        a = fmaf(w1[o * 4 + 2], feat2, a);
        a = fmaf(w1[o * 4 + 3], feat3, a);
        t1[o] = 0.5f * a * (1.0f + erff(a * 0.70710678118654752f));
    }
    int base = b * CC * 262144 + vox;
#pragma unroll
    for (int c = 0; c < 32; ++c) {
        float a = b2s[c];
#pragma unroll
        for (int o = 0; o < 16; ++o) a = fmaf(w2[c * 16 + o], t1[o], a);
        h[base + c * 262144] = a;
    }
}

// ---------------- fused spectral conv along one axis ----------------
// AXIS: 2 = z (stride 1), 1 = y (stride 64), 0 = x (stride 4096)
// LDS float layout (17152 floats = 67 KB -> 2 blocks/CU):
//  region A @0     : xbuf  [128 lines][66]          (8448 f)  -> later mspec float2 [128][33]
//  region B @8448  : spec  float2 [4 s][32 c][32 m] (8192 f)  -> later ybuf float [128][67] (8576 f)
//  roots   @17024  : float2[64]                     (128 f)
template <int AXIS, bool ACCUM>
__global__ __launch_bounds__(STH, 4) void spectral_kernel(
    const float* __restrict__ h, float* __restrict__ sout,
    const float2* __restrict__ w)
{
    __shared__ float lds[17152];
    float*  xm    = lds;
    float2* mspec = (float2*)lds;
    float2* spec  = (float2*)(lds + 8448);
    float*  ybuf  = lds + 8448;
    float2* roots = (float2*)(lds + 17024);

    const int tid = threadIdx.x;
    const int site0 = blockIdx.x * NSITE;        // 16384 sites total
    const int b  = site0 >> 12;
    const int q0 = site0 & 4095;

    if (tid < 64) {
        float ss, sc;
        sincosf((float)tid * (6.283185307179586f / 64.0f), &ss, &sc);
        roots[tid] = make_float2(sc, ss);
    }

    // ---- load lines into LDS: xbuf[line = c*4+s][t] ----
#pragma unroll
    for (int k = 0; k < 16; ++k) {
        int e = tid + k * STH;
        int c, s, t;
        if (AXIS == 2) { t = e & 63; s = (e >> 6) & 3; c = e >> 8; }
        else           { s = e & 3;  t = (e >> 2) & 63; c = e >> 8; }
        int q = q0 + s;
        int addr;
        if (AXIS == 2)      addr = (b * CC + c) * 262144 + q * 64 + t;
        else if (AXIS == 1) addr = (b * CC + c) * 262144 + (q >> 6) * 4096 + t * 64 + (q & 63);
        else                addr = (b * CC + c) * 262144 + t * 4096 + (q >> 6) * 64 + (q & 63);
        xm[(c * NSITE + s) * 66 + t] = h[addr];
    }
    __syncthreads();

    // ---- forward DFT: spec[s][c][m] = (1/8) sum_t x[t] e^{-2pi i m t /64}, m<32 ----
    {
        const int mt = tid & 7;     // mode tile (4 modes)
        const int lt = tid >> 3;    // line tile (2 lines), 0..63
        const int m0 = mt * 4;
        float ar[2][4], ai[2][4];
#pragma unroll
        for (int j = 0; j < 2; ++j)
#pragma unroll
            for (int i = 0; i < 4; ++i) { ar[j][i] = 0.0f; ai[j][i] = 0.0f; }
        int idx0 = 0, idx1 = 0, idx2 = 0, idx3 = 0;
        for (int t = 0; t < 64; ++t) {
            float xv[2];
#pragma unroll
            for (int j = 0; j < 2; ++j) xv[j] = xm[(lt * 2 + j) * 66 + t];
            float2 r0 = roots[idx0], r1 = roots[idx1], r2 = roots[idx2], r3 = roots[idx3];
            idx0 = (idx0 + m0 + 0) & 63;
            idx1 = (idx1 + m0 + 1) & 63;
            idx2 = (idx2 + m0 + 2) & 63;
            idx3 = (idx3 + m0 + 3) & 63;
#pragma unroll
            for (int j = 0; j < 2; ++j) {
                ar[j][0] = fmaf(xv[j], r0.x, ar[j][0]); ai[j][0] = fmaf(-xv[j], r0.y, ai[j][0]);
                ar[j][1] = fmaf(xv[j], r1.x, ar[j][1]); ai[j][1] = fmaf(-xv[j], r1.y, ai[j][1]);
                ar[j][2] = fmaf(xv[j], r2.x, ar[j][2]); ai[j][2] = fmaf(-xv[j], r2.y, ai[j][2]);
                ar[j][3] = fmaf(xv[j], r3.x, ar[j][3]); ai[j][3] = fmaf(-xv[j], r3.y, ai[j][3]);
            }
        }
#pragma unroll
        for (int j = 0; j < 2; ++j) {
            int line = lt * 2 + j;
            int c = line >> 2, s = line & 3;
#pragma unroll
            for (int i = 0; i < 4; ++i)
                spec[(s * CC + c) * MM + m0 + i] =
                    make_float2(ar[j][i] * 0.125f, ai[j][i] * 0.125f);
        }
    }
    __syncthreads();

    // ---- mode mix: mspec[o*4+s][m] = sum_i spec[s][i][m] * w[i][o][m] ----
    {
        const int m  = tid & 31;
        const int sp = (tid >> 5) & 1;   // site pair (2 sites)
        const int ot = tid >> 6;         // out tile (4 outs), 0..7
        float ar[2][4], ai[2][4];
#pragma unroll
        for (int js = 0; js < 2; ++js)
#pragma unroll
            for (int jo = 0; jo < 4; ++jo) { ar[js][jo] = 0.0f; ai[js][jo] = 0.0f; }
        for (int i = 0; i < CC; ++i) {
            float2 sv[2];
#pragma unroll
            for (int js = 0; js < 2; ++js) sv[js] = spec[((sp * 2 + js) * CC + i) * MM + m];
#pragma unroll
            for (int jo = 0; jo < 4; ++jo) {
                float2 wv = w[(i * CC + ot * 4 + jo) * MM + m];
#pragma unroll
                for (int js = 0; js < 2; ++js) {
                    ar[js][jo] = fmaf(sv[js].x, wv.x, fmaf(-sv[js].y, wv.y, ar[js][jo]));
                    ai[js][jo] = fmaf(sv[js].x, wv.y, fmaf( sv[js].y, wv.x, ai[js][jo]));
                }
            }
        }
        __syncthreads();   // all spec reads (region B) complete before ybuf writes later
#pragma unroll
        for (int js = 0; js < 2; ++js) {
            int s = sp * 2 + js;
#pragma unroll
            for (int jo = 0; jo < 4; ++jo) {
                int o = ot * 4 + jo;
                mspec[(o * NSITE + s) * 33 + m] = make_float2(ar[js][jo], ai[js][jo]);
            }
        }
    }
    __syncthreads();

    // ---- inverse DFT: y[t] = 0.125*(m0r + 2*sum_{m=1}^{31}(re*cos - im*sin)) ----
    {
        const int tt = tid & 7;     // t tile (8 t)
        const int lt = tid >> 3;    // line tile (2 lines), 0..63
        float acc[2][8];
#pragma unroll
        for (int j = 0; j < 2; ++j) {
            float m0r = mspec[(lt * 2 + j) * 33].x;
#pragma unroll
            for (int u = 0; u < 8; ++u) acc[j][u] = 0.5f * m0r;
        }
        for (int m = 1; m < 32; ++m) {
            float2 sv[2];
#pragma unroll
            for (int j = 0; j < 2; ++j) sv[j] = mspec[(lt * 2 + j) * 33 + m];
            int idx = (m * tt * 8) & 63;
#pragma unroll
            for (int u = 0; u < 8; ++u) {
                float2 rt = roots[idx];
                idx = (idx + m) & 63;
#pragma unroll
                for (int j = 0; j < 2; ++j) {
                    acc[j][u] = fmaf(sv[j].x, rt.x, acc[j][u]);
                    acc[j][u] = fmaf(-sv[j].y, rt.y, acc[j][u]);
                }
            }
        }
#pragma unroll
        for (int j = 0; j < 2; ++j)
#pragma unroll
            for (int u = 0; u < 8; ++u)
                ybuf[(lt * 2 + j) * 67 + tt * 8 + u] = acc[j][u] * 0.25f;
    }
    __syncthreads();

    // ---- store / accumulate to s ----
#pragma unroll
    for (int k = 0; k < 16; ++k) {
        int e = tid + k * STH;
        int o, s, t;
        if (AXIS == 2) { t = e & 63; s = (e >> 6) & 3; o = e >> 8; }
        else           { s = e & 3;  t = (e >> 2) & 63; o = e >> 8; }
        int q = q0 + s;
        int addr;
        if (AXIS == 2)      addr = (b * CC + o) * 262144 + q * 64 + t;
        else if (AXIS == 1) addr = (b * CC + o) * 262144 + (q >> 6) * 4096 + t * 64 + (q & 63);
        else                addr = (b * CC + o) * 262144 + t * 4096 + (q >> 6) * 64 + (q & 63);
        float v = ybuf[(o * NSITE + s) * 67 + t];
        if (ACCUM) sout[addr] += v;
        else       sout[addr] = v;
    }
}

// ---------------- per-layer MLP: h = (mw2 @ gelu(mw1 @ s + mb1) + mb2) + h ----------------
// chunked t1 (16-wide) keeps live regs ~80 -> 4 waves/SIMD; float4 LDS weight reads.
__global__ __launch_bounds__(256, 4) void mlp_kernel(
    const float* __restrict__ sin_, float* hio,
    const float* __restrict__ mw1, const float* __restrict__ mb1,
    const float* __restrict__ mw2, const float* __restrict__ mb2)
{
    __shared__ float w1[2048];    // [64 o][32 i]
    __shared__ float w2t[2048];   // transposed: [64 o][32 c]
    __shared__ float bb1[64], bb2[32];
    int tid = threadIdx.x;
#pragma unroll
    for (int k = 0; k < 8; ++k) {
        int i = tid + k * 256;
        w1[i] = mw1[i];
        w2t[(i & 63) * 32 + (i >> 6)] = mw2[i];   // i = c*64+o
    }
    if (tid < 64) bb1[tid] = mb1[tid];
    if (tid < 32) bb2[tid] = mb2[tid];
    __syncthreads();

    const float4* w1v  = (const float4*)w1;
    const float4* w2tv = (const float4*)w2t;

    int v = blockIdx.x * 256 + tid;
    int b = v >> 18;
    int vox = v & 262143;
    int base = b * CC * 262144 + vox;

    float sv[32];
#pragma unroll
    for (int i = 0; i < 32; ++i) sv[i] = sin_[base + i * 262144];

    float acc[32];
#pragma unroll
    for (int c = 0; c < 32; ++c) acc[c] = bb2[c];

#pragma unroll
    for (int ch = 0; ch < 4; ++ch) {
        float t1c[16];
#pragma unroll
        for (int o16 = 0; o16 < 16; ++o16) {
            int o = ch * 16 + o16;
            float a = bb1[o];
#pragma unroll
            for (int i4 = 0; i4 < 8; ++i4) {
                float4 wv = w1v[o * 8 + i4];
                a = fmaf(wv.x, sv[i4 * 4 + 0], a);
                a = fmaf(wv.y, sv[i4 * 4 + 1], a);
                a = fmaf(wv.z, sv[i4 * 4 + 2], a);
                a = fmaf(wv.w, sv[i4 * 4 + 3], a);
            }
            t1c[o16] = 0.5f * a * (1.0f + erff(a * 0.70710678118654752f));
        }
#pragma unroll
        for (int o16 = 0; o16 < 16; ++o16) {
            int o = ch * 16 + o16;
            float tv = t1c[o16];
#pragma unroll
            for (int c4 = 0; c4 < 8; ++c4) {
                float4 wv = w2tv[o * 8 + c4];
                acc[c4 * 4 + 0] = fmaf(wv.x, tv, acc[c4 * 4 + 0]);
                acc[c4 * 4 + 1] = fmaf(wv.y, tv, acc[c4 * 4 + 1]);
                acc[c4 * 4 + 2] = fmaf(wv.z, tv, acc[c4 * 4 + 2]);
                acc[c4 * 4 + 3] = fmaf(wv.w, tv, acc[c4 * 4 + 3]);
            }
        }
    }
#pragma unroll
    for (int c = 0; c < 32; ++c) hio[base + c * 262144] += acc[c];
}

extern "C" void kernel_launch(void* const* d_in, const int* in_sizes, int n_in,
                              void* d_out, int out_size, void* d_ws, size_t ws_size,
                              hipStream_t stream) {
    const float* x   = (const float*)d_in[0];
    const float* lw1 = (const float*)d_in[1];
    const float* lb1 = (const float*)d_in[2];
    const float* lw2 = (const float*)d_in[3];
    const float* lb2 = (const float*)d_in[4];
    const float* wx  = (const float*)d_in[5];
    const float* wy  = (const float*)d_in[6];
    const float* wz  = (const float*)d_in[7];
    const float* mw1 = (const float*)d_in[8];
    const float* mb1 = (const float*)d_in[9];
    const float* mw2 = (const float*)d_in[10];
    const float* mb2 = (const float*)d_in[11];

    float* h = (float*)d_out;   // h resident in d_out
    float* s = (float*)d_ws;    // spectral accumulator (128 MB)

    lift_kernel<<<4096, 256, 0, stream>>>(x, lw1, lb1, lw2, lb2, h);

    for (int l = 0; l < 6; ++l) {
        const float2* wxl = (const float2*)wx + l * 32768;
        const float2* wyl = (const float2*)wy + l * 32768;
        const float2* wzl = (const float2*)wz + l * 32768;
        spectral_kernel<2, false><<<4096, STH, 0, stream>>>(h, s, wzl);
        spectral_kernel<1, true ><<<4096, STH, 0, stream>>>(h, s, wyl);
        spectral_kernel<0, true ><<<4096, STH, 0, stream>>>(h, s, wxl);
        mlp_kernel<<<4096, 256, 0, stream>>>(s, h,
            mw1 + l * 2048, mb1 + l * 64, mw2 + l * 2048, mb2 + l * 32);
    }
}

// Round 5
// 10821.264 us; speedup vs baseline: 2.9786x; 2.9786x over previous
//
#include <hip/hip_runtime.h>
#include <math.h>

// FNO3D encoder: B=4, CIN=1, 64^3, W=32 ch, L=6 layers, M=32 modes.
// h lives in d_out (fp32 [4][32][64][64][64]); spectral accumulator s in d_ws.

#define BB 4
#define CC 32
#define NN 64
#define MM 32
#define NSITE 4          // perpendicular sites per block (67KB LDS -> 2 blocks/CU)
#define STH 512          // spectral block threads

// ---------------- lift: [x,gx,gy,gz] -> 16 (gelu) -> 32 ----------------
__global__ __launch_bounds__(256) void lift_kernel(
    const float* __restrict__ x,
    const float* __restrict__ lw1, const float* __restrict__ lb1,
    const float* __restrict__ lw2, const float* __restrict__ lb2,
    float* __restrict__ h)
{
    __shared__ float w1[64], b1s[16], w2[512], b2s[32];
    int tid = threadIdx.x;
    if (tid < 64) w1[tid] = lw1[tid];
    if (tid < 16) b1s[tid] = lb1[tid];
    for (int i = tid; i < 512; i += 256) w2[i] = lw2[i];
    if (tid < 32) b2s[tid] = lb2[tid];
    __syncthreads();

    int v = blockIdx.x * 256 + tid;          // 0 .. 1M-1
    int b = v >> 18;
    int vox = v & 262143;
    float feat0 = x[b * 262144 + vox];
    float feat1 = (float)(vox >> 12)        * (1.0f / 63.0f);
    float feat2 = (float)((vox >> 6) & 63)  * (1.0f / 63.0f);
    float feat3 = (float)(vox & 63)         * (1.0f / 63.0f);

    float t1[16];
#pragma unroll
    for (int o = 0; o < 16; ++o) {
        float a = b1s[o];
        a = fmaf(w1[o * 4 + 0], feat0, a);
        a = fmaf(w1[o * 4 + 1], feat1, a);
        a = fmaf(w1[o * 4 + 2], feat2, a);
        a = fmaf(w1[o * 4 + 3], feat3, a);
        t1[o] = 0.5f * a * (1.0f + erff(a * 0.70710678118654752f));
    }
    int base = b * CC * 262144 + vox;
#pragma unroll
    for (int c = 0; c < 32; ++c) {
        float a = b2s[c];
#pragma unroll
        for (int o = 0; o < 16; ++o) a = fmaf(w2[c * 16 + o], t1[o], a);
        h[base + c * 262144] = a;
    }
}

// ---------------- fused spectral conv along one axis ----------------
// AXIS: 2 = z (stride 1), 1 = y (stride 64), 0 = x (stride 4096)
// LDS float layout (17152 floats = 67 KB -> 2 blocks/CU):
//  region A @0     : xbuf  [128 lines][66]          (8448 f)  -> later mspec float2 [128][33]
//  region B @8448  : spec  float2 [4 s][32 c][32 m] (8192 f)  -> later ybuf float [128][67] (8576 f)
//  roots   @17024  : float2[64]                     (128 f)
template <int AXIS, bool ACCUM>
__global__ __launch_bounds__(STH, 4) void spectral_kernel(
    const float* __restrict__ h, float* __restrict__ sout,
    const float2* __restrict__ w)
{
    __shared__ float lds[17152];
    float*  xm    = lds;
    float2* mspec = (float2*)lds;
    float2* spec  = (float2*)(lds + 8448);
    float*  ybuf  = lds + 8448;
    float2* roots = (float2*)(lds + 17024);

    const int tid = threadIdx.x;
    const int site0 = blockIdx.x * NSITE;        // 16384 sites total
    const int b  = site0 >> 12;
    const int q0 = site0 & 4095;

    if (tid < 64) {
        float ss, sc;
        sincosf((float)tid * (6.283185307179586f / 64.0f), &ss, &sc);
        roots[tid] = make_float2(sc, ss);
    }

    // ---- load lines into LDS: xbuf[line = c*4+s][t] ----
#pragma unroll
    for (int k = 0; k < 16; ++k) {
        int e = tid + k * STH;
        int c, s, t;
        if (AXIS == 2) { t = e & 63; s = (e >> 6) & 3; c = e >> 8; }
        else           { s = e & 3;  t = (e >> 2) & 63; c = e >> 8; }
        int q = q0 + s;
        int addr;
        if (AXIS == 2)      addr = (b * CC + c) * 262144 + q * 64 + t;
        else if (AXIS == 1) addr = (b * CC + c) * 262144 + (q >> 6) * 4096 + t * 64 + (q & 63);
        else                addr = (b * CC + c) * 262144 + t * 4096 + (q >> 6) * 64 + (q & 63);
        xm[(c * NSITE + s) * 66 + t] = h[addr];
    }
    __syncthreads();

    // ---- forward DFT: spec[s][c][m] = (1/8) sum_t x[t] e^{-2pi i m t /64}, m<32 ----
    {
        const int mt = tid & 7;     // mode tile (4 modes)
        const int lt = tid >> 3;    // line tile (2 lines), 0..63
        const int m0 = mt * 4;
        float ar[2][4], ai[2][4];
#pragma unroll
        for (int j = 0; j < 2; ++j)
#pragma unroll
            for (int i = 0; i < 4; ++i) { ar[j][i] = 0.0f; ai[j][i] = 0.0f; }
        int idx0 = 0, idx1 = 0, idx2 = 0, idx3 = 0;
        for (int t = 0; t < 64; ++t) {
            float xv[2];
#pragma unroll
            for (int j = 0; j < 2; ++j) xv[j] = xm[(lt * 2 + j) * 66 + t];
            float2 r0 = roots[idx0], r1 = roots[idx1], r2 = roots[idx2], r3 = roots[idx3];
            idx0 = (idx0 + m0 + 0) & 63;
            idx1 = (idx1 + m0 + 1) & 63;
            idx2 = (idx2 + m0 + 2) & 63;
            idx3 = (idx3 + m0 + 3) & 63;
#pragma unroll
            for (int j = 0; j < 2; ++j) {
                ar[j][0] = fmaf(xv[j], r0.x, ar[j][0]); ai[j][0] = fmaf(-xv[j], r0.y, ai[j][0]);
                ar[j][1] = fmaf(xv[j], r1.x, ar[j][1]); ai[j][1] = fmaf(-xv[j], r1.y, ai[j][1]);
                ar[j][2] = fmaf(xv[j], r2.x, ar[j][2]); ai[j][2] = fmaf(-xv[j], r2.y, ai[j][2]);
                ar[j][3] = fmaf(xv[j], r3.x, ar[j][3]); ai[j][3] = fmaf(-xv[j], r3.y, ai[j][3]);
            }
        }
#pragma unroll
        for (int j = 0; j < 2; ++j) {
            int line = lt * 2 + j;
            int c = line >> 2, s = line & 3;
#pragma unroll
            for (int i = 0; i < 4; ++i)
                spec[(s * CC + c) * MM + m0 + i] =
                    make_float2(ar[j][i] * 0.125f, ai[j][i] * 0.125f);
        }
    }
    __syncthreads();

    // ---- mode mix: mspec[o*4+s][m] = sum_i spec[s][i][m] * w[i][o][m] ----
    {
        const int m  = tid & 31;
        const int sp = (tid >> 5) & 1;   // site pair (2 sites)
        const int ot = tid >> 6;         // out tile (4 outs), 0..7
        float ar[2][4], ai[2][4];
#pragma unroll
        for (int js = 0; js < 2; ++js)
#pragma unroll
            for (int jo = 0; jo < 4; ++jo) { ar[js][jo] = 0.0f; ai[js][jo] = 0.0f; }
        for (int i = 0; i < CC; ++i) {
            float2 sv[2];
#pragma unroll
            for (int js = 0; js < 2; ++js) sv[js] = spec[((sp * 2 + js) * CC + i) * MM + m];
#pragma unroll
            for (int jo = 0; jo < 4; ++jo) {
                float2 wv = w[(i * CC + ot * 4 + jo) * MM + m];
#pragma unroll
                for (int js = 0; js < 2; ++js) {
                    ar[js][jo] = fmaf(sv[js].x, wv.x, fmaf(-sv[js].y, wv.y, ar[js][jo]));
                    ai[js][jo] = fmaf(sv[js].x, wv.y, fmaf( sv[js].y, wv.x, ai[js][jo]));
                }
            }
        }
        __syncthreads();   // all spec reads (region B) complete before ybuf writes later
#pragma unroll
        for (int js = 0; js < 2; ++js) {
            int s = sp * 2 + js;
#pragma unroll
            for (int jo = 0; jo < 4; ++jo) {
                int o = ot * 4 + jo;
                mspec[(o * NSITE + s) * 33 + m] = make_float2(ar[js][jo], ai[js][jo]);
            }
        }
    }
    __syncthreads();

    // ---- inverse DFT: y[t] = 0.125*(m0r + 2*sum_{m=1}^{31}(re*cos - im*sin)) ----
    {
        const int tt = tid & 7;     // t tile (8 t)
        const int lt = tid >> 3;    // line tile (2 lines), 0..63
        float acc[2][8];
#pragma unroll
        for (int j = 0; j < 2; ++j) {
            float m0r = mspec[(lt * 2 + j) * 33].x;
#pragma unroll
            for (int u = 0; u < 8; ++u) acc[j][u] = 0.5f * m0r;
        }
        for (int m = 1; m < 32; ++m) {
            float2 sv[2];
#pragma unroll
            for (int j = 0; j < 2; ++j) sv[j] = mspec[(lt * 2 + j) * 33 + m];
            int idx = (m * tt * 8) & 63;
#pragma unroll
            for (int u = 0; u < 8; ++u) {
                float2 rt = roots[idx];
                idx = (idx + m) & 63;
#pragma unroll
                for (int j = 0; j < 2; ++j) {
                    acc[j][u] = fmaf(sv[j].x, rt.x, acc[j][u]);
                    acc[j][u] = fmaf(-sv[j].y, rt.y, acc[j][u]);
                }
            }
        }
#pragma unroll
        for (int j = 0; j < 2; ++j)
#pragma unroll
            for (int u = 0; u < 8; ++u)
                ybuf[(lt * 2 + j) * 67 + tt * 8 + u] = acc[j][u] * 0.25f;
    }
    __syncthreads();

    // ---- store / accumulate to s ----
#pragma unroll
    for (int k = 0; k < 16; ++k) {
        int e = tid + k * STH;
        int o, s, t;
        if (AXIS == 2) { t = e & 63; s = (e >> 6) & 3; o = e >> 8; }
        else           { s = e & 3;  t = (e >> 2) & 63; o = e >> 8; }
        int q = q0 + s;
        int addr;
        if (AXIS == 2)      addr = (b * CC + o) * 262144 + q * 64 + t;
        else if (AXIS == 1) addr = (b * CC + o) * 262144 + (q >> 6) * 4096 + t * 64 + (q & 63);
        else                addr = (b * CC + o) * 262144 + t * 4096 + (q >> 6) * 64 + (q & 63);
        float v = ybuf[(o * NSITE + s) * 67 + t];
        if (ACCUM) sout[addr] += v;
        else       sout[addr] = v;
    }
}

// ---------------- per-layer MLP: h = (mw2 @ gelu(mw1 @ s + mb1) + mb2) + h ----------------
// v3: NO LDS, NO launch-bounds cap. Weights are wave-uniform -> compiler emits
// scalar (s_load) reads from the constant-cached 16KB weight set. Chunked t1
// keeps all array indices compile-time (no scratch).
__global__ __launch_bounds__(256) void mlp_kernel(
    const float* __restrict__ sin_, float* __restrict__ hio,
    const float* __restrict__ mw1, const float* __restrict__ mb1,
    const float* __restrict__ mw2, const float* __restrict__ mb2)
{
    const float4* w1v = (const float4*)mw1;   // [64 o][8  i4]
    const float4* w2v = (const float4*)mw2;   // [32 c][16 o4]

    int tid = threadIdx.x;
    int v = blockIdx.x * 256 + tid;
    int b = v >> 18;
    int vox = v & 262143;
    int base = b * CC * 262144 + vox;

    float sv[32];
#pragma unroll
    for (int i = 0; i < 32; ++i) sv[i] = sin_[base + i * 262144];

    float acc[32];
#pragma unroll
    for (int c = 0; c < 32; ++c) acc[c] = mb2[c];

#pragma unroll
    for (int ch = 0; ch < 4; ++ch) {
        float t1c[16];
#pragma unroll
        for (int o16 = 0; o16 < 16; ++o16) {
            int o = ch * 16 + o16;
            float a = mb1[o];
#pragma unroll
            for (int i4 = 0; i4 < 8; ++i4) {
                float4 wv = w1v[o * 8 + i4];
                a = fmaf(wv.x, sv[i4 * 4 + 0], a);
                a = fmaf(wv.y, sv[i4 * 4 + 1], a);
                a = fmaf(wv.z, sv[i4 * 4 + 2], a);
                a = fmaf(wv.w, sv[i4 * 4 + 3], a);
            }
            t1c[o16] = 0.5f * a * (1.0f + erff(a * 0.70710678118654752f));
        }
#pragma unroll
        for (int c = 0; c < 32; ++c) {
#pragma unroll
            for (int o4 = 0; o4 < 4; ++o4) {
                float4 wv = w2v[c * 16 + ch * 4 + o4];
                acc[c] = fmaf(wv.x, t1c[o4 * 4 + 0], acc[c]);
                acc[c] = fmaf(wv.y, t1c[o4 * 4 + 1], acc[c]);
                acc[c] = fmaf(wv.z, t1c[o4 * 4 + 2], acc[c]);
                acc[c] = fmaf(wv.w, t1c[o4 * 4 + 3], acc[c]);
            }
        }
    }
#pragma unroll
    for (int c = 0; c < 32; ++c) hio[base + c * 262144] += acc[c];
}

extern "C" void kernel_launch(void* const* d_in, const int* in_sizes, int n_in,
                              void* d_out, int out_size, void* d_ws, size_t ws_size,
                              hipStream_t stream) {
    const float* x   = (const float*)d_in[0];
    const float* lw1 = (const float*)d_in[1];
    const float* lb1 = (const float*)d_in[2];
    const float* lw2 = (const float*)d_in[3];
    const float* lb2 = (const float*)d_in[4];
    const float* wx  = (const float*)d_in[5];
    const float* wy  = (const float*)d_in[6];
    const float* wz  = (const float*)d_in[7];
    const float* mw1 = (const float*)d_in[8];
    const float* mb1 = (const float*)d_in[9];
    const float* mw2 = (const float*)d_in[10];
    const float* mb2 = (const float*)d_in[11];

    float* h = (float*)d_out;   // h resident in d_out
    float* s = (float*)d_ws;    // spectral accumulator (128 MB)

    lift_kernel<<<4096, 256, 0, stream>>>(x, lw1, lb1, lw2, lb2, h);

    for (int l = 0; l < 6; ++l) {
        const float2* wxl = (const float2*)wx + l * 32768;
        const float2* wyl = (const float2*)wy + l * 32768;
        const float2* wzl = (const float2*)wz + l * 32768;
        spectral_kernel<2, false><<<4096, STH, 0, stream>>>(h, s, wzl);
        spectral_kernel<1, true ><<<4096, STH, 0, stream>>>(h, s, wyl);
        spectral_kernel<0, true ><<<4096, STH, 0, stream>>>(h, s, wxl);
        mlp_kernel<<<4096, 256, 0, stream>>>(s, h,
            mw1 + l * 2048, mb1 + l * 64, mw2 + l * 2048, mb2 + l * 32);
    }
}

// Round 6
// 10507.555 us; speedup vs baseline: 3.0675x; 1.0299x over previous
//
#include <hip/hip_runtime.h>
#include <math.h>

// FNO3D encoder: B=4, CIN=1, 64^3, W=32 ch, L=6 layers, M=32 modes.
// h lives in d_out (fp32 [4][32][64][64][64]); spectral accumulator s in d_ws.

#define BB 4
#define CC 32
#define NN 64
#define MM 32
#define NSITE 8          // perpendicular sites per block
#define STH 512          // spectral block threads

// ---------------- lift: [x,gx,gy,gz] -> 16 (gelu) -> 32 ----------------
__global__ __launch_bounds__(256) void lift_kernel(
    const float* __restrict__ x,
    const float* __restrict__ lw1, const float* __restrict__ lb1,
    const float* __restrict__ lw2, const float* __restrict__ lb2,
    float* __restrict__ h)
{
    __shared__ float w1[64], b1s[16], w2[512], b2s[32];
    int tid = threadIdx.x;
    if (tid < 64) w1[tid] = lw1[tid];
    if (tid < 16) b1s[tid] = lb1[tid];
    for (int i = tid; i < 512; i += 256) w2[i] = lw2[i];
    if (tid < 32) b2s[tid] = lb2[tid];
    __syncthreads();

    int v = blockIdx.x * 256 + tid;          // 0 .. 1M-1
    int b = v >> 18;
    int vox = v & 262143;
    float feat0 = x[b * 262144 + vox];
    float feat1 = (float)(vox >> 12)        * (1.0f / 63.0f);
    float feat2 = (float)((vox >> 6) & 63)  * (1.0f / 63.0f);
    float feat3 = (float)(vox & 63)         * (1.0f / 63.0f);

    float t1[16];
#pragma unroll
    for (int o = 0; o < 16; ++o) {
        float a = b1s[o];
        a = fmaf(w1[o * 4 + 0], feat0, a);
        a = fmaf(w1[o * 4 + 1], feat1, a);
        a = fmaf(w1[o * 4 + 2], feat2, a);
        a = fmaf(w1[o * 4 + 3], feat3, a);
        t1[o] = 0.5f * a * (1.0f + erff(a * 0.70710678118654752f));
    }
    int base = b * CC * 262144 + vox;
#pragma unroll
    for (int c = 0; c < 32; ++c) {
        float a = b2s[c];
#pragma unroll
        for (int o = 0; o < 16; ++o) a = fmaf(w2[c * 16 + o], t1[o], a);
        h[base + c * 262144] = a;
    }
}

// ---------------- fused spectral conv along one axis ----------------
// AXIS: 2 = z (stride 1), 1 = y (stride 64), 0 = x (stride 4096)
// LDS float layout (34176 floats = 133.5 KB):
//  region A @0      : xbuf  [256 lines][66]          (16896 f)  -> later mspec float2 [256][33]
//  region B @16896  : spec  float2 [8 s][32 c][32 m] (16384 f)  -> later ybuf float [256][67] (17152 f)
//  roots   @34048   : float2[64]                     (128 f)
// Real-signal conjugate folding halves fwd/inv DFT arithmetic (VALU-bound kernel).
template <int AXIS, bool ACCUM>
__global__ __launch_bounds__(STH) void spectral_kernel(
    const float* __restrict__ h, float* __restrict__ sout,
    const float2* __restrict__ w)
{
    __shared__ float lds[34176];
    float*  xm    = lds;
    float2* mspec = (float2*)lds;
    float2* spec  = (float2*)(lds + 16896);
    float*  ybuf  = lds + 16896;
    float2* roots = (float2*)(lds + 34048);

    const int tid = threadIdx.x;
    const int site0 = blockIdx.x * NSITE;        // 16384 sites total
    const int b  = site0 >> 12;
    const int q0 = site0 & 4095;

    if (tid < 64) {
        float ss, sc;
        sincosf((float)tid * (6.283185307179586f / 64.0f), &ss, &sc);
        roots[tid] = make_float2(sc, ss);
    }

    // ---- load lines into LDS: xbuf[line = c*8+s][t] ----
#pragma unroll
    for (int k = 0; k < 32; ++k) {
        int e = tid + k * STH;
        int c, s, t;
        if (AXIS == 2) { t = e & 63; s = (e >> 6) & 7; c = e >> 9; }
        else           { s = e & 7;  t = (e >> 3) & 63; c = e >> 9; }
        int q = q0 + s;
        int addr;
        if (AXIS == 2)      addr = (b * CC + c) * 262144 + q * 64 + t;
        else if (AXIS == 1) addr = (b * CC + c) * 262144 + (q >> 6) * 4096 + t * 64 + (q & 63);
        else                addr = (b * CC + c) * 262144 + t * 4096 + (q >> 6) * 64 + (q & 63);
        xm[(c * NSITE + s) * 66 + t] = h[addr];
    }
    __syncthreads();

    // ---- forward DFT (folded): spec[m] = 0.125 * [ x0 + (-1)^m x32
    //        + sum_{t=1}^{31} ( (x[t]+x[64-t])cos - i (x[t]-x[64-t])sin ) ] ----
    {
        const int mt = tid & 7;     // mode tile (4 modes)
        const int lt = tid >> 3;    // line tile (4 lines), 0..63
        const int m0 = mt * 4;
        float ar[4][4], ai[4][4];
#pragma unroll
        for (int j = 0; j < 4; ++j) {
            float x0  = xm[(lt * 4 + j) * 66 + 0];
            float x32 = xm[(lt * 4 + j) * 66 + 32];
#pragma unroll
            for (int i = 0; i < 4; ++i) {
                ar[j][i] = (i & 1) ? (x0 - x32) : (x0 + x32);   // (-1)^(m0+i) = (-1)^i
                ai[j][i] = 0.0f;
            }
        }
        int idx0 = m0 + 0, idx1 = m0 + 1, idx2 = m0 + 2, idx3 = m0 + 3;
        for (int t = 1; t < 32; ++t) {
            float p[4], q[4];
#pragma unroll
            for (int j = 0; j < 4; ++j) {
                float xa = xm[(lt * 4 + j) * 66 + t];
                float xb = xm[(lt * 4 + j) * 66 + 64 - t];
                p[j] = xa + xb;
                q[j] = xa - xb;
            }
            float2 r0 = roots[idx0], r1 = roots[idx1], r2 = roots[idx2], r3 = roots[idx3];
            idx0 = (idx0 + m0 + 0) & 63;
            idx1 = (idx1 + m0 + 1) & 63;
            idx2 = (idx2 + m0 + 2) & 63;
            idx3 = (idx3 + m0 + 3) & 63;
#pragma unroll
            for (int j = 0; j < 4; ++j) {
                ar[j][0] = fmaf(p[j], r0.x, ar[j][0]); ai[j][0] = fmaf(-q[j], r0.y, ai[j][0]);
                ar[j][1] = fmaf(p[j], r1.x, ar[j][1]); ai[j][1] = fmaf(-q[j], r1.y, ai[j][1]);
                ar[j][2] = fmaf(p[j], r2.x, ar[j][2]); ai[j][2] = fmaf(-q[j], r2.y, ai[j][2]);
                ar[j][3] = fmaf(p[j], r3.x, ar[j][3]); ai[j][3] = fmaf(-q[j], r3.y, ai[j][3]);
            }
        }
#pragma unroll
        for (int j = 0; j < 4; ++j) {
            int line = lt * 4 + j;
            int c = line >> 3, s = line & 7;
#pragma unroll
            for (int i = 0; i < 4; ++i)
                spec[(s * CC + c) * MM + m0 + i] =
                    make_float2(ar[j][i] * 0.125f, ai[j][i] * 0.125f);
        }
    }
    __syncthreads();

    // ---- mode mix: mspec[o*8+s][m] = sum_i spec[s][i][m] * w[i][o][m] ----
    {
        const int m  = tid & 31;
        const int st = (tid >> 5) & 1;   // site tile (4 sites)
        const int ot = tid >> 6;         // out tile (4 outs), 0..7
        float ar[4][4], ai[4][4];
#pragma unroll
        for (int js = 0; js < 4; ++js)
#pragma unroll
            for (int jo = 0; jo < 4; ++jo) { ar[js][jo] = 0.0f; ai[js][jo] = 0.0f; }
        for (int i = 0; i < CC; ++i) {
            float2 sv[4];
#pragma unroll
            for (int js = 0; js < 4; ++js) sv[js] = spec[((st * 4 + js) * CC + i) * MM + m];
#pragma unroll
            for (int jo = 0; jo < 4; ++jo) {
                float2 wv = w[(i * CC + ot * 4 + jo) * MM + m];
#pragma unroll
                for (int js = 0; js < 4; ++js) {
                    ar[js][jo] = fmaf(sv[js].x, wv.x, fmaf(-sv[js].y, wv.y, ar[js][jo]));
                    ai[js][jo] = fmaf(sv[js].x, wv.y, fmaf( sv[js].y, wv.x, ai[js][jo]));
                }
            }
        }
        __syncthreads();   // order: all spec reads (region B) complete before ybuf writes later
#pragma unroll
        for (int js = 0; js < 4; ++js) {
            int s = st * 4 + js;
#pragma unroll
            for (int jo = 0; jo < 4; ++jo) {
                int o = ot * 4 + jo;
                mspec[(o * NSITE + s) * 33 + m] = make_float2(ar[js][jo], ai[js][jo]);
            }
        }
    }
    __syncthreads();

    // ---- inverse DFT (folded): per pair p in 1..32:
    //   u = 0.5*m0r + sum re*cos(2pi m p/64), v = sum im*sin(2pi m p/64)
    //   y[p] = (u-v)/4, y[64-p] = (u+v)/4; y[0] = (0.5*m0r + sum re)/4 (lane tt==0)
    {
        const int tt = tid & 7;     // pair tile (4 pairs)
        const int lt = tid >> 3;    // line tile (4 lines), 0..63
        float u[4][4], vv[4][4], wsum[4], m0r[4];
#pragma unroll
        for (int j = 0; j < 4; ++j) {
            m0r[j] = mspec[(lt * 4 + j) * 33].x;
            wsum[j] = 0.0f;
#pragma unroll
            for (int jj = 0; jj < 4; ++jj) { u[j][jj] = 0.5f * m0r[j]; vv[j][jj] = 0.0f; }
        }
        const int p0 = tt * 4 + 1, p1 = tt * 4 + 2, p2 = tt * 4 + 3, p3 = tt * 4 + 4;
        int i0 = p0, i1 = p1, i2 = p2, i3 = p3;
        for (int m = 1; m < 32; ++m) {
            float2 sv[4];
#pragma unroll
            for (int j = 0; j < 4; ++j) sv[j] = mspec[(lt * 4 + j) * 33 + m];
            float2 r0 = roots[i0], r1 = roots[i1], r2 = roots[i2], r3 = roots[i3];
            i0 = (i0 + p0) & 63;
            i1 = (i1 + p1) & 63;
            i2 = (i2 + p2) & 63;
            i3 = (i3 + p3) & 63;
#pragma unroll
            for (int j = 0; j < 4; ++j) {
                u[j][0] = fmaf(sv[j].x, r0.x, u[j][0]); vv[j][0] = fmaf(sv[j].y, r0.y, vv[j][0]);
                u[j][1] = fmaf(sv[j].x, r1.x, u[j][1]); vv[j][1] = fmaf(sv[j].y, r1.y, vv[j][1]);
                u[j][2] = fmaf(sv[j].x, r2.x, u[j][2]); vv[j][2] = fmaf(sv[j].y, r2.y, vv[j][2]);
                u[j][3] = fmaf(sv[j].x, r3.x, u[j][3]); vv[j][3] = fmaf(sv[j].y, r3.y, vv[j][3]);
                wsum[j] += sv[j].x;
            }
        }
#pragma unroll
        for (int j = 0; j < 4; ++j) {
            int line = lt * 4 + j;
            ybuf[line * 67 + p0]               = (u[j][0] - vv[j][0]) * 0.25f;
            ybuf[line * 67 + ((64 - p0) & 63)] = (u[j][0] + vv[j][0]) * 0.25f;
            ybuf[line * 67 + p1]               = (u[j][1] - vv[j][1]) * 0.25f;
            ybuf[line * 67 + ((64 - p1) & 63)] = (u[j][1] + vv[j][1]) * 0.25f;
            ybuf[line * 67 + p2]               = (u[j][2] - vv[j][2]) * 0.25f;
            ybuf[line * 67 + ((64 - p2) & 63)] = (u[j][2] + vv[j][2]) * 0.25f;
            ybuf[line * 67 + p3]               = (u[j][3] - vv[j][3]) * 0.25f;
            ybuf[line * 67 + ((64 - p3) & 63)] = (u[j][3] + vv[j][3]) * 0.25f;
            if (tt == 0)
                ybuf[line * 67 + 0] = (0.5f * m0r[j] + wsum[j]) * 0.25f;
        }
    }
    __syncthreads();

    // ---- store / accumulate to s ----
#pragma unroll
    for (int k = 0; k < 32; ++k) {
        int e = tid + k * STH;
        int o, s, t;
        if (AXIS == 2) { t = e & 63; s = (e >> 6) & 7; o = e >> 9; }
        else           { s = e & 7;  t = (e >> 3) & 63; o = e >> 9; }
        int q = q0 + s;
        int addr;
        if (AXIS == 2)      addr = (b * CC + o) * 262144 + q * 64 + t;
        else if (AXIS == 1) addr = (b * CC + o) * 262144 + (q >> 6) * 4096 + t * 64 + (q & 63);
        else                addr = (b * CC + o) * 262144 + t * 4096 + (q >> 6) * 64 + (q & 63);
        float v = ybuf[(o * NSITE + s) * 67 + t];
        if (ACCUM) sout[addr] += v;
        else       sout[addr] = v;
    }
}

// ---------------- per-layer MLP: h = (mw2 @ gelu(mw1 @ s + mb1) + mb2) + h ----------------
// v3: NO LDS, NO launch-bounds cap. Weights are wave-uniform -> compiler emits
// scalar (s_load) reads from the constant-cached 16KB weight set. Chunked t1
// keeps all array indices compile-time (no scratch).
__global__ __launch_bounds__(256) void mlp_kernel(
    const float* __restrict__ sin_, float* __restrict__ hio,
    const float* __restrict__ mw1, const float* __restrict__ mb1,
    const float* __restrict__ mw2, const float* __restrict__ mb2)
{
    const float4* w1v = (const float4*)mw1;   // [64 o][8  i4]
    const float4* w2v = (const float4*)mw2;   // [32 c][16 o4]

    int tid = threadIdx.x;
    int v = blockIdx.x * 256 + tid;
    int b = v >> 18;
    int vox = v & 262143;
    int base = b * CC * 262144 + vox;

    float sv[32];
#pragma unroll
    for (int i = 0; i < 32; ++i) sv[i] = sin_[base + i * 262144];

    float acc[32];
#pragma unroll
    for (int c = 0; c < 32; ++c) acc[c] = mb2[c];

#pragma unroll
    for (int ch = 0; ch < 4; ++ch) {
        float t1c[16];
#pragma unroll
        for (int o16 = 0; o16 < 16; ++o16) {
            int o = ch * 16 + o16;
            float a = mb1[o];
#pragma unroll
            for (int i4 = 0; i4 < 8; ++i4) {
                float4 wv = w1v[o * 8 + i4];
                a = fmaf(wv.x, sv[i4 * 4 + 0], a);
                a = fmaf(wv.y, sv[i4 * 4 + 1], a);
                a = fmaf(wv.z, sv[i4 * 4 + 2], a);
                a = fmaf(wv.w, sv[i4 * 4 + 3], a);
            }
            t1c[o16] = 0.5f * a * (1.0f + erff(a * 0.70710678118654752f));
        }
#pragma unroll
        for (int c = 0; c < 32; ++c) {
#pragma unroll
            for (int o4 = 0; o4 < 4; ++o4) {
                float4 wv = w2v[c * 16 + ch * 4 + o4];
                acc[c] = fmaf(wv.x, t1c[o4 * 4 + 0], acc[c]);
                acc[c] = fmaf(wv.y, t1c[o4 * 4 + 1], acc[c]);
                acc[c] = fmaf(wv.z, t1c[o4 * 4 + 2], acc[c]);
                acc[c] = fmaf(wv.w, t1c[o4 * 4 + 3], acc[c]);
            }
        }
    }
#pragma unroll
    for (int c = 0; c < 32; ++c) hio[base + c * 262144] += acc[c];
}

extern "C" void kernel_launch(void* const* d_in, const int* in_sizes, int n_in,
                              void* d_out, int out_size, void* d_ws, size_t ws_size,
                              hipStream_t stream) {
    const float* x   = (const float*)d_in[0];
    const float* lw1 = (const float*)d_in[1];
    const float* lb1 = (const float*)d_in[2];
    const float* lw2 = (const float*)d_in[3];
    const float* lb2 = (const float*)d_in[4];
    const float* wx  = (const float*)d_in[5];
    const float* wy  = (const float*)d_in[6];
    const float* wz  = (const float*)d_in[7];
    const float* mw1 = (const float*)d_in[8];
    const float* mb1 = (const float*)d_in[9];
    const float* mw2 = (const float*)d_in[10];
    const float* mb2 = (const float*)d_in[11];

    float* h = (float*)d_out;   // h resident in d_out
    float* s = (float*)d_ws;    // spectral accumulator (128 MB)

    lift_kernel<<<4096, 256, 0, stream>>>(x, lw1, lb1, lw2, lb2, h);

    for (int l = 0; l < 6; ++l) {
        const float2* wxl = (const float2*)wx + l * 32768;
        const float2* wyl = (const float2*)wy + l * 32768;
        const float2* wzl = (const float2*)wz + l * 32768;
        spectral_kernel<2, false><<<2048, STH, 0, stream>>>(h, s, wzl);
        spectral_kernel<1, true ><<<2048, STH, 0, stream>>>(h, s, wyl);
        spectral_kernel<0, true ><<<2048, STH, 0, stream>>>(h, s, wxl);
        mlp_kernel<<<4096, 256, 0, stream>>>(s, h,
            mw1 + l * 2048, mb1 + l * 64, mw2 + l * 2048, mb2 + l * 32);
    }
}

// Round 7
// 10281.176 us; speedup vs baseline: 3.1351x; 1.0220x over previous
//
#include <hip/hip_runtime.h>
#include <math.h>

// FNO3D encoder: B=4, CIN=1, 64^3, W=32 ch, L=6 layers, M=32 modes.
// h lives in d_out (fp32 [4][32][64][64][64]); spectral accumulator s in d_ws.
// Layer schedule: y-pass (s=), x-pass (s+=), fused z-pass (z-spectral + MLP + h+=).

#define BB 4
#define CC 32
#define NN 64
#define MM 32
#define NSITE 8          // perpendicular sites per block
#define STH 512          // spectral block threads

// ---------------- lift: [x,gx,gy,gz] -> 16 (gelu) -> 32 ----------------
__global__ __launch_bounds__(256) void lift_kernel(
    const float* __restrict__ x,
    const float* __restrict__ lw1, const float* __restrict__ lb1,
    const float* __restrict__ lw2, const float* __restrict__ lb2,
    float* __restrict__ h)
{
    __shared__ float w1[64], b1s[16], w2[512], b2s[32];
    int tid = threadIdx.x;
    if (tid < 64) w1[tid] = lw1[tid];
    if (tid < 16) b1s[tid] = lb1[tid];
    for (int i = tid; i < 512; i += 256) w2[i] = lw2[i];
    if (tid < 32) b2s[tid] = lb2[tid];
    __syncthreads();

    int v = blockIdx.x * 256 + tid;          // 0 .. 1M-1
    int b = v >> 18;
    int vox = v & 262143;
    float feat0 = x[b * 262144 + vox];
    float feat1 = (float)(vox >> 12)        * (1.0f / 63.0f);
    float feat2 = (float)((vox >> 6) & 63)  * (1.0f / 63.0f);
    float feat3 = (float)(vox & 63)         * (1.0f / 63.0f);

    float t1[16];
#pragma unroll
    for (int o = 0; o < 16; ++o) {
        float a = b1s[o];
        a = fmaf(w1[o * 4 + 0], feat0, a);
        a = fmaf(w1[o * 4 + 1], feat1, a);
        a = fmaf(w1[o * 4 + 2], feat2, a);
        a = fmaf(w1[o * 4 + 3], feat3, a);
        t1[o] = 0.5f * a * (1.0f + erff(a * 0.70710678118654752f));
    }
    int base = b * CC * 262144 + vox;
#pragma unroll
    for (int c = 0; c < 32; ++c) {
        float a = b2s[c];
#pragma unroll
        for (int o = 0; o < 16; ++o) a = fmaf(w2[c * 16 + o], t1[o], a);
        h[base + c * 262144] = a;
    }
}

// ======== shared spectral phases (device functions operating on LDS) ========
// LDS float layout (34176 floats = 133.5 KB):
//  region A @0      : xbuf  [256 lines][66]          (16896 f)  -> later mspec float2 [256][33]
//  region B @16896  : spec  float2 [8 s][32 c][32 m] (16384 f)  -> later ybuf float [256][67] (17152 f)
//  roots   @34048   : float2[64]                     (128 f)

__device__ __forceinline__ void spectral_core(
    float* lds, int tid)
{
    float*  xm    = lds;
    float2* mspec = (float2*)lds;
    float2* spec  = (float2*)(lds + 16896);
    float*  ybuf  = lds + 16896;
    float2* roots = (float2*)(lds + 34048);

    // ---- forward DFT (folded): spec[m] = 0.125 * [ x0 + (-1)^m x32
    //        + sum_{t=1}^{31} ( (x[t]+x[64-t])cos - i (x[t]-x[64-t])sin ) ] ----
    {
        const int mt = tid & 7;     // mode tile (4 modes)
        const int lt = tid >> 3;    // line tile (4 lines), 0..63
        const int m0 = mt * 4;
        float ar[4][4], ai[4][4];
#pragma unroll
        for (int j = 0; j < 4; ++j) {
            float x0  = xm[(lt * 4 + j) * 66 + 0];
            float x32 = xm[(lt * 4 + j) * 66 + 32];
#pragma unroll
            for (int i = 0; i < 4; ++i) {
                ar[j][i] = (i & 1) ? (x0 - x32) : (x0 + x32);   // (-1)^(m0+i) = (-1)^i
                ai[j][i] = 0.0f;
            }
        }
        int idx0 = m0 + 0, idx1 = m0 + 1, idx2 = m0 + 2, idx3 = m0 + 3;
        for (int t = 1; t < 32; ++t) {
            float p[4], q[4];
#pragma unroll
            for (int j = 0; j < 4; ++j) {
                float xa = xm[(lt * 4 + j) * 66 + t];
                float xb = xm[(lt * 4 + j) * 66 + 64 - t];
                p[j] = xa + xb;
                q[j] = xa - xb;
            }
            float2 r0 = roots[idx0], r1 = roots[idx1], r2 = roots[idx2], r3 = roots[idx3];
            idx0 = (idx0 + m0 + 0) & 63;
            idx1 = (idx1 + m0 + 1) & 63;
            idx2 = (idx2 + m0 + 2) & 63;
            idx3 = (idx3 + m0 + 3) & 63;
#pragma unroll
            for (int j = 0; j < 4; ++j) {
                ar[j][0] = fmaf(p[j], r0.x, ar[j][0]); ai[j][0] = fmaf(-q[j], r0.y, ai[j][0]);
                ar[j][1] = fmaf(p[j], r1.x, ar[j][1]); ai[j][1] = fmaf(-q[j], r1.y, ai[j][1]);
                ar[j][2] = fmaf(p[j], r2.x, ar[j][2]); ai[j][2] = fmaf(-q[j], r2.y, ai[j][2]);
                ar[j][3] = fmaf(p[j], r3.x, ar[j][3]); ai[j][3] = fmaf(-q[j], r3.y, ai[j][3]);
            }
        }
#pragma unroll
        for (int j = 0; j < 4; ++j) {
            int line = lt * 4 + j;
            int c = line >> 3, s = line & 7;
#pragma unroll
            for (int i = 0; i < 4; ++i)
                spec[(s * CC + c) * MM + m0 + i] =
                    make_float2(ar[j][i] * 0.125f, ai[j][i] * 0.125f);
        }
    }
    __syncthreads();
}

__device__ __forceinline__ void spectral_mix_inv(
    float* lds, int tid, const float2* __restrict__ w)
{
    float2* mspec = (float2*)lds;
    float2* spec  = (float2*)(lds + 16896);
    float*  ybuf  = lds + 16896;
    float2* roots = (float2*)(lds + 34048);

    // ---- mode mix: mspec[o*8+s][m] = sum_i spec[s][i][m] * w[i][o][m] ----
    {
        const int m  = tid & 31;
        const int st = (tid >> 5) & 1;   // site tile (4 sites)
        const int ot = tid >> 6;         // out tile (4 outs), 0..7
        float ar[4][4], ai[4][4];
#pragma unroll
        for (int js = 0; js < 4; ++js)
#pragma unroll
            for (int jo = 0; jo < 4; ++jo) { ar[js][jo] = 0.0f; ai[js][jo] = 0.0f; }
        for (int i = 0; i < CC; ++i) {
            float2 sv[4];
#pragma unroll
            for (int js = 0; js < 4; ++js) sv[js] = spec[((st * 4 + js) * CC + i) * MM + m];
#pragma unroll
            for (int jo = 0; jo < 4; ++jo) {
                float2 wv = w[(i * CC + ot * 4 + jo) * MM + m];
#pragma unroll
                for (int js = 0; js < 4; ++js) {
                    ar[js][jo] = fmaf(sv[js].x, wv.x, fmaf(-sv[js].y, wv.y, ar[js][jo]));
                    ai[js][jo] = fmaf(sv[js].x, wv.y, fmaf( sv[js].y, wv.x, ai[js][jo]));
                }
            }
        }
        __syncthreads();   // all spec reads (region B) done before ybuf writes later
#pragma unroll
        for (int js = 0; js < 4; ++js) {
            int s = st * 4 + js;
#pragma unroll
            for (int jo = 0; jo < 4; ++jo) {
                int o = ot * 4 + jo;
                mspec[(o * NSITE + s) * 33 + m] = make_float2(ar[js][jo], ai[js][jo]);
            }
        }
    }
    __syncthreads();

    // ---- inverse DFT (folded): per pair p in 1..32:
    //   u = 0.5*m0r + sum re*cos, v = sum im*sin; y[p]=(u-v)/4, y[64-p]=(u+v)/4
    {
        const int tt = tid & 7;     // pair tile (4 pairs)
        const int lt = tid >> 3;    // line tile (4 lines), 0..63
        float u[4][4], vv[4][4], wsum[4], m0r[4];
#pragma unroll
        for (int j = 0; j < 4; ++j) {
            m0r[j] = mspec[(lt * 4 + j) * 33].x;
            wsum[j] = 0.0f;
#pragma unroll
            for (int jj = 0; jj < 4; ++jj) { u[j][jj] = 0.5f * m0r[j]; vv[j][jj] = 0.0f; }
        }
        const int p0 = tt * 4 + 1, p1 = tt * 4 + 2, p2 = tt * 4 + 3, p3 = tt * 4 + 4;
        int i0 = p0, i1 = p1, i2 = p2, i3 = p3;
        for (int m = 1; m < 32; ++m) {
            float2 sv[4];
#pragma unroll
            for (int j = 0; j < 4; ++j) sv[j] = mspec[(lt * 4 + j) * 33 + m];
            float2 r0 = roots[i0], r1 = roots[i1], r2 = roots[i2], r3 = roots[i3];
            i0 = (i0 + p0) & 63;
            i1 = (i1 + p1) & 63;
            i2 = (i2 + p2) & 63;
            i3 = (i3 + p3) & 63;
#pragma unroll
            for (int j = 0; j < 4; ++j) {
                u[j][0] = fmaf(sv[j].x, r0.x, u[j][0]); vv[j][0] = fmaf(sv[j].y, r0.y, vv[j][0]);
                u[j][1] = fmaf(sv[j].x, r1.x, u[j][1]); vv[j][1] = fmaf(sv[j].y, r1.y, vv[j][1]);
                u[j][2] = fmaf(sv[j].x, r2.x, u[j][2]); vv[j][2] = fmaf(sv[j].y, r2.y, vv[j][2]);
                u[j][3] = fmaf(sv[j].x, r3.x, u[j][3]); vv[j][3] = fmaf(sv[j].y, r3.y, vv[j][3]);
                wsum[j] += sv[j].x;
            }
        }
#pragma unroll
        for (int j = 0; j < 4; ++j) {
            int line = lt * 4 + j;
            ybuf[line * 67 + p0]               = (u[j][0] - vv[j][0]) * 0.25f;
            ybuf[line * 67 + ((64 - p0) & 63)] = (u[j][0] + vv[j][0]) * 0.25f;
            ybuf[line * 67 + p1]               = (u[j][1] - vv[j][1]) * 0.25f;
            ybuf[line * 67 + ((64 - p1) & 63)] = (u[j][1] + vv[j][1]) * 0.25f;
            ybuf[line * 67 + p2]               = (u[j][2] - vv[j][2]) * 0.25f;
            ybuf[line * 67 + ((64 - p2) & 63)] = (u[j][2] + vv[j][2]) * 0.25f;
            ybuf[line * 67 + p3]               = (u[j][3] - vv[j][3]) * 0.25f;
            ybuf[line * 67 + ((64 - p3) & 63)] = (u[j][3] + vv[j][3]) * 0.25f;
            if (tt == 0)
                ybuf[line * 67 + 0] = (0.5f * m0r[j] + wsum[j]) * 0.25f;
        }
    }
    __syncthreads();
}

// ---------------- y/x spectral passes (store / accumulate to s) ----------------
// AXIS: 1 = y (stride 64), 0 = x (stride 4096)
template <int AXIS, bool ACCUM>
__global__ __launch_bounds__(STH) void spectral_kernel(
    const float* __restrict__ h, float* __restrict__ sout,
    const float2* __restrict__ w)
{
    __shared__ float lds[34176];
    float*  xm    = lds;
    float*  ybuf  = lds + 16896;
    float2* roots = (float2*)(lds + 34048);

    const int tid = threadIdx.x;
    const int site0 = blockIdx.x * NSITE;        // 16384 sites total
    const int b  = site0 >> 12;
    const int q0 = site0 & 4095;

    if (tid < 64) {
        float ss, sc;
        sincosf((float)tid * (6.283185307179586f / 64.0f), &ss, &sc);
        roots[tid] = make_float2(sc, ss);
    }

    // ---- load lines into LDS: xbuf[line = c*8+s][t] ----
#pragma unroll
    for (int k = 0; k < 32; ++k) {
        int e = tid + k * STH;
        int s = e & 7, t = (e >> 3) & 63, c = e >> 9;
        int q = q0 + s;
        int addr;
        if (AXIS == 1) addr = (b * CC + c) * 262144 + (q >> 6) * 4096 + t * 64 + (q & 63);
        else           addr = (b * CC + c) * 262144 + t * 4096 + (q >> 6) * 64 + (q & 63);
        xm[(c * NSITE + s) * 66 + t] = h[addr];
    }
    __syncthreads();

    spectral_core(lds, tid);
    spectral_mix_inv(lds, tid, w);

    // ---- store / accumulate to s ----
#pragma unroll
    for (int k = 0; k < 32; ++k) {
        int e = tid + k * STH;
        int s = e & 7, t = (e >> 3) & 63, o = e >> 9;
        int q = q0 + s;
        int addr;
        if (AXIS == 1) addr = (b * CC + o) * 262144 + (q >> 6) * 4096 + t * 64 + (q & 63);
        else           addr = (b * CC + o) * 262144 + t * 4096 + (q >> 6) * 64 + (q & 63);
        float v = ybuf[(o * NSITE + s) * 67 + t];
        if (ACCUM) sout[addr] += v;
        else       sout[addr] = v;
    }
}

// ---------------- fused z spectral + per-voxel MLP + residual ----------------
// s_in holds y+x contributions; this kernel adds the z contribution, applies
// the layer MLP (32 -> 64 gelu -> 32), and does h += result.
// AXIS=2: per-voxel accesses are lane-consecutive (coalesced).
__global__ __launch_bounds__(STH) void spectral_mlp_z_kernel(
    const float* __restrict__ hin, float* __restrict__ hio,
    const float* __restrict__ s_in,
    const float2* __restrict__ w,
    const float* __restrict__ mw1, const float* __restrict__ mb1,
    const float* __restrict__ mw2, const float* __restrict__ mb2)
{
    __shared__ float lds[34176];
    float*  xm    = lds;
    float*  ybuf  = lds + 16896;
    float2* roots = (float2*)(lds + 34048);

    const int tid = threadIdx.x;
    const int site0 = blockIdx.x * NSITE;        // 16384 sites total
    const int b  = site0 >> 12;
    const int q0 = site0 & 4095;

    if (tid < 64) {
        float ss, sc;
        sincosf((float)tid * (6.283185307179586f / 64.0f), &ss, &sc);
        roots[tid] = make_float2(sc, ss);
    }

    // ---- load lines into LDS (z-axis: t contiguous) ----
#pragma unroll
    for (int k = 0; k < 32; ++k) {
        int e = tid + k * STH;
        int t = e & 63, s = (e >> 6) & 7, c = e >> 9;
        int q = q0 + s;
        xm[(c * NSITE + s) * 66 + t] = hin[(b * CC + c) * 262144 + q * 64 + t];
    }
    __syncthreads();

    spectral_core(lds, tid);
    spectral_mix_inv(lds, tid, w);

    // ---- epilogue: per-voxel MLP + residual ----
    // thread -> voxel: s = tid>>6 (0..7), t = tid&63 ; addr lane-consecutive in t.
    {
        const int s = tid >> 6;
        const int t = tid & 63;
        const int q = q0 + s;
        const int g = (b * CC) * 262144 + q * 64 + t;   // channel stride 262144

        const float4* w1v = (const float4*)mw1;   // [64 o][8  i4]
        const float4* w2v = (const float4*)mw2;   // [32 c][16 o4]

        float out[32];
#pragma unroll
        for (int c = 0; c < 32; ++c)
            out[c] = ybuf[(c * NSITE + s) * 67 + t] + s_in[g + c * 262144];

        float acc[32];
#pragma unroll
        for (int c = 0; c < 32; ++c) acc[c] = mb2[c];

#pragma unroll
        for (int ch = 0; ch < 4; ++ch) {
            float t1c[16];
#pragma unroll
            for (int o16 = 0; o16 < 16; ++o16) {
                int o = ch * 16 + o16;
                float a = mb1[o];
#pragma unroll
                for (int i4 = 0; i4 < 8; ++i4) {
                    float4 wv = w1v[o * 8 + i4];
                    a = fmaf(wv.x, out[i4 * 4 + 0], a);
                    a = fmaf(wv.y, out[i4 * 4 + 1], a);
                    a = fmaf(wv.z, out[i4 * 4 + 2], a);
                    a = fmaf(wv.w, out[i4 * 4 + 3], a);
                }
                t1c[o16] = 0.5f * a * (1.0f + erff(a * 0.70710678118654752f));
            }
#pragma unroll
            for (int c = 0; c < 32; ++c) {
#pragma unroll
                for (int o4 = 0; o4 < 4; ++o4) {
                    float4 wv = w2v[c * 16 + ch * 4 + o4];
                    acc[c] = fmaf(wv.x, t1c[o4 * 4 + 0], acc[c]);
                    acc[c] = fmaf(wv.y, t1c[o4 * 4 + 1], acc[c]);
                    acc[c] = fmaf(wv.z, t1c[o4 * 4 + 2], acc[c]);
                    acc[c] = fmaf(wv.w, t1c[o4 * 4 + 3], acc[c]);
                }
            }
        }
#pragma unroll
        for (int c = 0; c < 32; ++c) hio[g + c * 262144] += acc[c];
    }
}

extern "C" void kernel_launch(void* const* d_in, const int* in_sizes, int n_in,
                              void* d_out, int out_size, void* d_ws, size_t ws_size,
                              hipStream_t stream) {
    const float* x   = (const float*)d_in[0];
    const float* lw1 = (const float*)d_in[1];
    const float* lb1 = (const float*)d_in[2];
    const float* lw2 = (const float*)d_in[3];
    const float* lb2 = (const float*)d_in[4];
    const float* wx  = (const float*)d_in[5];
    const float* wy  = (const float*)d_in[6];
    const float* wz  = (const float*)d_in[7];
    const float* mw1 = (const float*)d_in[8];
    const float* mb1 = (const float*)d_in[9];
    const float* mw2 = (const float*)d_in[10];
    const float* mb2 = (const float*)d_in[11];

    float* h = (float*)d_out;   // h resident in d_out
    float* s = (float*)d_ws;    // spectral accumulator (128 MB)

    lift_kernel<<<4096, 256, 0, stream>>>(x, lw1, lb1, lw2, lb2, h);

    for (int l = 0; l < 6; ++l) {
        const float2* wxl = (const float2*)wx + l * 32768;
        const float2* wyl = (const float2*)wy + l * 32768;
        const float2* wzl = (const float2*)wz + l * 32768;
        spectral_kernel<1, false><<<2048, STH, 0, stream>>>(h, s, wyl);
        spectral_kernel<0, true ><<<2048, STH, 0, stream>>>(h, s, wxl);
        spectral_mlp_z_kernel<<<2048, STH, 0, stream>>>(h, h, s, wzl,
            mw1 + l * 2048, mb1 + l * 64, mw2 + l * 2048, mb2 + l * 32);
    }
}